// Round 1
// baseline (286.701 us; speedup 1.0000x reference)
//
#include <hip/hip_runtime.h>
#include <hip/hip_fp16.h>
#include <cstdint>
#include <cstddef>

// OccupancyModel: feats = grid[round(clip(p*127))]  (2M x 16 gather)
//   h1 = relu(feats @ W1^T + b1)   (16 -> 64)
//   h2 = relu(h1 @ W2^T + b2)      (64 -> 64)
//   occ = tanh(h2 @ W3^T + b3)     (64 -> 1)
//
// Strategy: fp16 MFMA (mfma_f32_16x16x32_f16, fp32 accumulate), computing
// H^T = W @ feats^T so points stay on the MFMA n-dim (col = lane&15) in all
// layers. Layer1->Layer2 fragment relayout is then a 4-lane cross-quad
// shuffle (ds_bpermute), no LDS round-trip, no barriers.
// One wave processes 16 points per tile iteration; 12 MFMAs/tile.

typedef _Float16 half8 __attribute__((ext_vector_type(8)));
typedef float float4v __attribute__((ext_vector_type(4)));

__device__ inline uint32_t pack_f16x2(float a, float b) {
    // RTN conversions (v_cvt_f16_f32) for accuracy margin; packed to 1 dword
    union { _Float16 h[2]; uint32_t u; } v;
    v.h[0] = (_Float16)a;
    v.h[1] = (_Float16)b;
    return v.u;
}

__global__ __launch_bounds__(256) void occ_mlp_kernel(
    const float* __restrict__ pts,
    const float* __restrict__ grid,
    const float* __restrict__ W1, const float* __restrict__ b1,
    const float* __restrict__ W2, const float* __restrict__ b2,
    const float* __restrict__ W3, const float* __restrict__ b3,
    float* __restrict__ out, int nPoints)
{
    const int lane = threadIdx.x & 63;
    const int l15  = lane & 15;
    const int quad = lane >> 4;
    const int wavesPerBlock = blockDim.x >> 6;
    const int waveId = blockIdx.x * wavesPerBlock + (threadIdx.x >> 6);
    const int nWaves = gridDim.x * wavesPerBlock;

    // ---- loop-invariant per-wave weight fragments ----
    // MFMA A-operand layout: A[m = lane&15][k = quad*8 + j], j in 0..7.
    // Layer1: A1[t] = W1[16t + m][k], K=16 zero-padded to 32 (quads 2,3 = 0).
    half8 A1[4];
#pragma unroll
    for (int t = 0; t < 4; ++t) {
        half8 f = {};
        if (quad < 2) {
            const float* row = W1 + (16 * t + l15) * 16 + quad * 8;
#pragma unroll
            for (int j = 0; j < 8; ++j) f[j] = (_Float16)row[j];
        }
        A1[t] = f;
    }
    // Layer2: A2[t][kk] = W2[16t + m][32*kk + 8*quad + j]
    half8 A2[4][2];
#pragma unroll
    for (int t = 0; t < 4; ++t)
#pragma unroll
        for (int kk = 0; kk < 2; ++kk) {
            const float* row = W2 + (16 * t + l15) * 64 + 32 * kk + 8 * quad;
            half8 f;
#pragma unroll
            for (int j = 0; j < 8; ++j) f[j] = (_Float16)row[j];
            A2[t][kk] = f;
        }
    // C/D layout: col = lane&15 (point), row = quad*4 + reg (hidden-in-tile).
    // Fold biases into accumulator init; w3 in matching layout for layer3 dot.
    float4v bias1[4], bias2[4];
    float w3v[4][4];
#pragma unroll
    for (int t = 0; t < 4; ++t)
#pragma unroll
        for (int r = 0; r < 4; ++r) {
            int h = 16 * t + 4 * quad + r;
            bias1[t][r] = b1[h];
            bias2[t][r] = b2[h];
            w3v[t][r]   = W3[h];
        }
    const float bias3 = b3[0];

    // Cross-quad shuffle plan for layer1->layer2 B-fragment relayout:
    // lane needs B2[k = 32kk + 8*quad + j][point l15]; source value lives in
    // lane l15 + 16*quad' with quad' = (2q)&3 (j<4) or (2q+1)&3 (j>=4),
    // tile t' = 2kk + (quad>>1), packed-half dword r>>1.
    const int src0 = l15 + 16 * ((2 * quad) & 3);
    const int src1 = l15 + 16 * ((2 * quad + 1) & 3);
    const bool sel = (quad >> 1) != 0;

    const int nTiles = (nPoints + 15) >> 4;
    for (int tile = waveId; tile < nTiles; tile += nWaves) {
        const int p = tile * 16 + l15;
        const int pc = p < nPoints ? p : nPoints - 1;

        // ---- gather: grid row of point (lane&15) ----
        const float px = pts[3 * pc + 0];
        const float py = pts[3 * pc + 1];
        const float pz = pts[3 * pc + 2];
        // jnp.round == round-half-even == rintf (default rounding mode)
        const int ix = (int)rintf(fminf(fmaxf(px * 127.0f, 0.0f), 127.0f));
        const int iy = (int)rintf(fminf(fmaxf(py * 127.0f, 0.0f), 127.0f));
        const int iz = (int)rintf(fminf(fmaxf(pz * 127.0f, 0.0f), 127.0f));
        const int ofs = ((((ix << 7) | iy) << 7) | iz) << 4;  // *16 feats
        const float* g = grid + ofs;

        // B1 frag: feats[point l15][k = quad*8 + j]; quads 2,3 are K-padding
        half8 bfrag = {};
        if (quad < 2) {
            const float4* gp = reinterpret_cast<const float4*>(g + quad * 8);
            const float4 f0 = gp[0];
            const float4 f1 = gp[1];
            bfrag[0] = (_Float16)f0.x; bfrag[1] = (_Float16)f0.y;
            bfrag[2] = (_Float16)f0.z; bfrag[3] = (_Float16)f0.w;
            bfrag[4] = (_Float16)f1.x; bfrag[5] = (_Float16)f1.y;
            bfrag[6] = (_Float16)f1.z; bfrag[7] = (_Float16)f1.w;
        }

        // ---- layer 1: H1^T[16t + 4q + r][point] ----
        float4v C1[4];
#pragma unroll
        for (int t = 0; t < 4; ++t) {
            C1[t] = bias1[t];
            C1[t] = __builtin_amdgcn_mfma_f32_16x16x32_f16(A1[t], bfrag, C1[t], 0, 0, 0);
        }

        // relu + fp16 pack: P[t][d] = halves (r=2d, 2d+1)
        uint32_t P[4][2];
#pragma unroll
        for (int t = 0; t < 4; ++t) {
            const float v0 = fmaxf(C1[t][0], 0.0f);
            const float v1 = fmaxf(C1[t][1], 0.0f);
            const float v2 = fmaxf(C1[t][2], 0.0f);
            const float v3 = fmaxf(C1[t][3], 0.0f);
            P[t][0] = pack_f16x2(v0, v1);
            P[t][1] = pack_f16x2(v2, v3);
        }

        // ---- cross-quad shuffle into layer-2 B fragments ----
        union Frag { uint32_t u[4]; half8 h; } B2[2];
#pragma unroll
        for (int kk = 0; kk < 2; ++kk) {
            const uint32_t x0a = (uint32_t)__shfl((int)P[2 * kk    ][0], src0);
            const uint32_t x0b = (uint32_t)__shfl((int)P[2 * kk + 1][0], src0);
            const uint32_t x1a = (uint32_t)__shfl((int)P[2 * kk    ][1], src0);
            const uint32_t x1b = (uint32_t)__shfl((int)P[2 * kk + 1][1], src0);
            const uint32_t y0a = (uint32_t)__shfl((int)P[2 * kk    ][0], src1);
            const uint32_t y0b = (uint32_t)__shfl((int)P[2 * kk + 1][0], src1);
            const uint32_t y1a = (uint32_t)__shfl((int)P[2 * kk    ][1], src1);
            const uint32_t y1b = (uint32_t)__shfl((int)P[2 * kk + 1][1], src1);
            B2[kk].u[0] = sel ? x0b : x0a;
            B2[kk].u[1] = sel ? x1b : x1a;
            B2[kk].u[2] = sel ? y0b : y0a;
            B2[kk].u[3] = sel ? y1b : y1a;
        }

        // ---- layer 2: H2^T ----
        float4v C2[4];
#pragma unroll
        for (int t = 0; t < 4; ++t) C2[t] = bias2[t];
#pragma unroll
        for (int kk = 0; kk < 2; ++kk)
#pragma unroll
            for (int t = 0; t < 4; ++t)
                C2[t] = __builtin_amdgcn_mfma_f32_16x16x32_f16(A2[t][kk], B2[kk].h, C2[t], 0, 0, 0);

        // ---- layer 3: dot(relu(h2), w3) reduced across quads ----
        float z = 0.0f;
#pragma unroll
        for (int t = 0; t < 4; ++t)
#pragma unroll
            for (int r = 0; r < 4; ++r)
                z = fmaf(fmaxf(C2[t][r], 0.0f), w3v[t][r], z);
        z += __shfl_xor(z, 16);
        z += __shfl_xor(z, 32);
        const float o = tanhf(z + bias3);
        if (lane < 16 && p < nPoints) out[p] = o;  // coalesced 64B store
    }
}

extern "C" void kernel_launch(void* const* d_in, const int* in_sizes, int n_in,
                              void* d_out, int out_size, void* d_ws, size_t ws_size,
                              hipStream_t stream)
{
    const float* pts  = (const float*)d_in[0];
    const float* grid = (const float*)d_in[1];
    const float* W1   = (const float*)d_in[2];
    const float* b1   = (const float*)d_in[3];
    const float* W2   = (const float*)d_in[4];
    const float* b2   = (const float*)d_in[5];
    const float* W3   = (const float*)d_in[6];
    const float* b3   = (const float*)d_in[7];
    float* out = (float*)d_out;
    const int nPoints = in_sizes[0] / 3;

    // 2048 blocks x 4 waves = 8192 waves; 131072 tiles -> exactly 16/wave
    occ_mlp_kernel<<<dim3(2048), dim3(256), 0, stream>>>(
        pts, grid, W1, b1, W2, b2, W3, b3, out, nPoints);
}

// Round 2
// 271.604 us; speedup vs baseline: 1.0556x; 1.0556x over previous
//
#include <hip/hip_runtime.h>
#include <hip/hip_fp16.h>
#include <cstdint>
#include <cstddef>

// OccupancyModel: feats = grid[round(clip(p*127))]  (2M x 16 gather)
//   h1 = relu(feats @ W1^T + b1)   (16 -> 64)
//   h2 = relu(h1 @ W2^T + b2)      (64 -> 64)
//   occ = tanh(h2 @ W3^T + b3)     (64 -> 1)
//
// fp16 MFMA (mfma_f32_16x16x32_f16, fp32 accumulate), H^T = W @ feats^T so
// points stay on the MFMA n-dim (col = lane&15). Layer1->Layer2 relayout is
// a 4-lane cross-quad shuffle — no LDS, no barriers.
//
// R2 change: latency-bound at 128us (VALU 36% / MFMA 8% / HBM 15%). Batch
// 4 tiles (64 points) per wave iteration: all 12 pts loads, then all 8
// gather dwordx4s issued before any compute -> 4x memory-level parallelism.
// Epilogue fused into one coalesced 256B store.

typedef _Float16 half8 __attribute__((ext_vector_type(8)));
typedef float float4v __attribute__((ext_vector_type(4)));

__device__ inline uint32_t pack_f16x2(float a, float b) {
    union { _Float16 h[2]; uint32_t u; } v;
    v.h[0] = (_Float16)a;
    v.h[1] = (_Float16)b;
    return v.u;
}

__global__ __launch_bounds__(256) void occ_mlp_kernel(
    const float* __restrict__ pts,
    const float* __restrict__ grid,
    const float* __restrict__ W1, const float* __restrict__ b1,
    const float* __restrict__ W2, const float* __restrict__ b2,
    const float* __restrict__ W3, const float* __restrict__ b3,
    float* __restrict__ out, int nPoints)
{
    const int lane = threadIdx.x & 63;
    const int l15  = lane & 15;
    const int quad = lane >> 4;
    const int wavesPerBlock = blockDim.x >> 6;
    const int waveId = blockIdx.x * wavesPerBlock + (threadIdx.x >> 6);
    const int nWaves = gridDim.x * wavesPerBlock;

    // ---- loop-invariant per-wave weight fragments ----
    // A-operand layout: A[m = lane&15][k = quad*8 + j], j in 0..7.
    half8 A1[4];
#pragma unroll
    for (int t = 0; t < 4; ++t) {
        half8 f = {};
        if (quad < 2) {
            const float* row = W1 + (16 * t + l15) * 16 + quad * 8;
#pragma unroll
            for (int j = 0; j < 8; ++j) f[j] = (_Float16)row[j];
        }
        A1[t] = f;
    }
    half8 A2[4][2];
#pragma unroll
    for (int t = 0; t < 4; ++t)
#pragma unroll
        for (int kk = 0; kk < 2; ++kk) {
            const float* row = W2 + (16 * t + l15) * 64 + 32 * kk + 8 * quad;
            half8 f;
#pragma unroll
            for (int j = 0; j < 8; ++j) f[j] = (_Float16)row[j];
            A2[t][kk] = f;
        }
    // C/D layout: col = lane&15 (point), row = quad*4 + reg.
    float4v bias1[4], bias2[4];
    float w3v[4][4];
#pragma unroll
    for (int t = 0; t < 4; ++t)
#pragma unroll
        for (int r = 0; r < 4; ++r) {
            int h = 16 * t + 4 * quad + r;
            bias1[t][r] = b1[h];
            bias2[t][r] = b2[h];
            w3v[t][r]   = W3[h];
        }
    const float bias3 = b3[0];

    // layer1->layer2 cross-quad shuffle plan (see R1 derivation)
    const int src0 = l15 + 16 * ((2 * quad) & 3);
    const int src1 = l15 + 16 * ((2 * quad + 1) & 3);
    const bool sel = (quad >> 1) != 0;

    const int nTiles = (nPoints + 15) >> 4;
    // 4 contiguous tiles (64 points) per batch
    for (int tb = waveId * 4; tb < nTiles; tb += nWaves * 4) {

        // ---- phase A: all 4 tiles' point loads + index math ----
        int ofs[4];
#pragma unroll
        for (int u = 0; u < 4; ++u) {
            int p = (tb + u) * 16 + l15;
            int pc = p < nPoints ? p : nPoints - 1;
            const float px = pts[3 * pc + 0];
            const float py = pts[3 * pc + 1];
            const float pz = pts[3 * pc + 2];
            const int ix = (int)rintf(fminf(fmaxf(px * 127.0f, 0.0f), 127.0f));
            const int iy = (int)rintf(fminf(fmaxf(py * 127.0f, 0.0f), 127.0f));
            const int iz = (int)rintf(fminf(fmaxf(pz * 127.0f, 0.0f), 127.0f));
            ofs[u] = ((((ix << 7) | iy) << 7) | iz) << 4;
        }

        // ---- phase B: issue all 8 gathers (quads 0-1; quads 2-3 = K pad) ----
        float4 g0[4] = {}, g1[4] = {};
#pragma unroll
        for (int u = 0; u < 4; ++u) {
            if (quad < 2) {
                const float4* gp = reinterpret_cast<const float4*>(grid + ofs[u] + quad * 8);
                g0[u] = gp[0];
                g1[u] = gp[1];
            }
        }

        // ---- phase C: per-tile MLP ----
        float o[4];
#pragma unroll
        for (int u = 0; u < 4; ++u) {
            half8 bfrag = {};
            if (quad < 2) {
                bfrag[0] = (_Float16)g0[u].x; bfrag[1] = (_Float16)g0[u].y;
                bfrag[2] = (_Float16)g0[u].z; bfrag[3] = (_Float16)g0[u].w;
                bfrag[4] = (_Float16)g1[u].x; bfrag[5] = (_Float16)g1[u].y;
                bfrag[6] = (_Float16)g1[u].z; bfrag[7] = (_Float16)g1[u].w;
            }

            // layer 1
            float4v C1[4];
#pragma unroll
            for (int t = 0; t < 4; ++t) {
                C1[t] = bias1[t];
                C1[t] = __builtin_amdgcn_mfma_f32_16x16x32_f16(A1[t], bfrag, C1[t], 0, 0, 0);
            }

            // relu + fp16 pack
            uint32_t P[4][2];
#pragma unroll
            for (int t = 0; t < 4; ++t) {
                const float v0 = fmaxf(C1[t][0], 0.0f);
                const float v1 = fmaxf(C1[t][1], 0.0f);
                const float v2 = fmaxf(C1[t][2], 0.0f);
                const float v3 = fmaxf(C1[t][3], 0.0f);
                P[t][0] = pack_f16x2(v0, v1);
                P[t][1] = pack_f16x2(v2, v3);
            }

            // cross-quad shuffle into layer-2 B fragments
            union Frag { uint32_t u[4]; half8 h; } B2[2];
#pragma unroll
            for (int kk = 0; kk < 2; ++kk) {
                const uint32_t x0a = (uint32_t)__shfl((int)P[2 * kk    ][0], src0);
                const uint32_t x0b = (uint32_t)__shfl((int)P[2 * kk + 1][0], src0);
                const uint32_t x1a = (uint32_t)__shfl((int)P[2 * kk    ][1], src0);
                const uint32_t x1b = (uint32_t)__shfl((int)P[2 * kk + 1][1], src0);
                const uint32_t y0a = (uint32_t)__shfl((int)P[2 * kk    ][0], src1);
                const uint32_t y0b = (uint32_t)__shfl((int)P[2 * kk + 1][0], src1);
                const uint32_t y1a = (uint32_t)__shfl((int)P[2 * kk    ][1], src1);
                const uint32_t y1b = (uint32_t)__shfl((int)P[2 * kk + 1][1], src1);
                B2[kk].u[0] = sel ? x0b : x0a;
                B2[kk].u[1] = sel ? x1b : x1a;
                B2[kk].u[2] = sel ? y0b : y0a;
                B2[kk].u[3] = sel ? y1b : y1a;
            }

            // layer 2
            float4v C2[4];
#pragma unroll
            for (int t = 0; t < 4; ++t) C2[t] = bias2[t];
#pragma unroll
            for (int kk = 0; kk < 2; ++kk)
#pragma unroll
                for (int t = 0; t < 4; ++t)
                    C2[t] = __builtin_amdgcn_mfma_f32_16x16x32_f16(A2[t][kk], B2[kk].h, C2[t], 0, 0, 0);

            // layer 3: dot(relu(h2), w3), reduce across quads
            float z = 0.0f;
#pragma unroll
            for (int t = 0; t < 4; ++t)
#pragma unroll
                for (int r = 0; r < 4; ++r)
                    z = fmaf(fmaxf(C2[t][r], 0.0f), w3v[t][r], z);
            z += __shfl_xor(z, 16);
            z += __shfl_xor(z, 32);
            o[u] = tanhf(z + bias3);
        }

        // ---- fused epilogue: one coalesced 256B store (lane -> point tb*16+lane)
        const float osel = (quad == 0) ? o[0] : (quad == 1) ? o[1]
                         : (quad == 2) ? o[2] : o[3];
        const int pstore = tb * 16 + lane;
        if (pstore < nPoints) out[pstore] = osel;
    }
}

extern "C" void kernel_launch(void* const* d_in, const int* in_sizes, int n_in,
                              void* d_out, int out_size, void* d_ws, size_t ws_size,
                              hipStream_t stream)
{
    const float* pts  = (const float*)d_in[0];
    const float* grid = (const float*)d_in[1];
    const float* W1   = (const float*)d_in[2];
    const float* b1   = (const float*)d_in[3];
    const float* W2   = (const float*)d_in[4];
    const float* b2   = (const float*)d_in[5];
    const float* W3   = (const float*)d_in[6];
    const float* b3   = (const float*)d_in[7];
    float* out = (float*)d_out;
    const int nPoints = in_sizes[0] / 3;

    // 2048 blocks x 4 waves = 8192 waves; 131072 tiles = 4 batches of 4/wave
    occ_mlp_kernel<<<dim3(2048), dim3(256), 0, stream>>>(
        pts, grid, W1, b1, W2, b2, W3, b3, out, nPoints);
}

// Round 3
// 270.840 us; speedup vs baseline: 1.0586x; 1.0028x over previous
//
#include <hip/hip_runtime.h>
#include <hip/hip_fp16.h>
#include <cstdint>
#include <cstddef>

// OccupancyModel: feats = grid[round(clip(p*127))]  (2M x 16 gather)
//   h1 = relu(feats @ W1^T + b1)   (16 -> 64)
//   h2 = relu(h1 @ W2^T + b2)      (64 -> 64)
//   occ = tanh(h2 @ W3^T + b3)     (64 -> 1)
//
// fp16 MFMA (mfma_f32_16x16x32_f16, fp32 acc), H^T = W @ feats^T: points on
// the MFMA n-dim (col = lane&15); layer1->layer2 relayout = cross-quad
// shuffles, no LDS barriers.
//
// R3: R2's 4-tile load batching was defeated by the compiler (VGPR=80 proves
// the gathers were sunk back to their uses -> serial chain, latency-bound at
// 117us with every pipe idle). Fixes:
//   * __builtin_amdgcn_sched_barrier(0) pins all 8 gather dwordx4s before
//     any compute -> real 4x memory-level parallelism per wave.
//   * b1 folded into the layer-1 K-padding slot (k=16, bfrag=1.0) -> frees
//     16 VGPRs of bias regs.
//   * tanhf -> 1 - 2*rcp(exp(2z)+1)  (v_exp + v_rcp; saturates correctly).

typedef _Float16 half8 __attribute__((ext_vector_type(8)));
typedef float float4v __attribute__((ext_vector_type(4)));

__device__ inline uint32_t pack_f16x2(float a, float b) {
    union { _Float16 h[2]; uint32_t u; } v;
    v.h[0] = (_Float16)a;
    v.h[1] = (_Float16)b;
    return v.u;
}

__global__ __launch_bounds__(256) void occ_mlp_kernel(
    const float* __restrict__ pts,
    const float* __restrict__ grid,
    const float* __restrict__ W1, const float* __restrict__ b1,
    const float* __restrict__ W2, const float* __restrict__ b2,
    const float* __restrict__ W3, const float* __restrict__ b3,
    float* __restrict__ out, int nPoints)
{
    const int lane = threadIdx.x & 63;
    const int l15  = lane & 15;
    const int quad = lane >> 4;
    const int wavesPerBlock = blockDim.x >> 6;
    const int waveId = blockIdx.x * wavesPerBlock + (threadIdx.x >> 6);
    const int nWaves = gridDim.x * wavesPerBlock;

    // ---- loop-invariant weight fragments ----
    // A layout: A[m = lane&15][k = quad*8 + j].  Layer1 K=16 padded to 32;
    // b1 folded at k=16 (quad2, j=0) with bfrag's k=16 slot = 1.0.
    half8 A1[4];
#pragma unroll
    for (int t = 0; t < 4; ++t) {
        half8 f = {};
        if (quad < 2) {
            const float* row = W1 + (16 * t + l15) * 16 + quad * 8;
#pragma unroll
            for (int j = 0; j < 8; ++j) f[j] = (_Float16)row[j];
        } else if (quad == 2) {
            f[0] = (_Float16)b1[16 * t + l15];
        }
        A1[t] = f;
    }
    half8 A2[4][2];
#pragma unroll
    for (int t = 0; t < 4; ++t)
#pragma unroll
        for (int kk = 0; kk < 2; ++kk) {
            const float* row = W2 + (16 * t + l15) * 64 + 32 * kk + 8 * quad;
            half8 f;
#pragma unroll
            for (int j = 0; j < 8; ++j) f[j] = (_Float16)row[j];
            A2[t][kk] = f;
        }
    // C/D layout: col = lane&15 (point), row = quad*4 + reg.
    float4v bias2[4];
    float w3v[4][4];
#pragma unroll
    for (int t = 0; t < 4; ++t)
#pragma unroll
        for (int r = 0; r < 4; ++r) {
            int h = 16 * t + 4 * quad + r;
            bias2[t][r] = b2[h];
            w3v[t][r]   = W3[h];
        }
    const float bias3 = b3[0];

    // layer1->layer2 cross-quad shuffle plan
    const int src0 = l15 + 16 * ((2 * quad) & 3);
    const int src1 = l15 + 16 * ((2 * quad + 1) & 3);
    const bool sel = (quad >> 1) != 0;

    const int nTiles = (nPoints + 15) >> 4;
    for (int tb = waveId * 4; tb < nTiles; tb += nWaves * 4) {

        // ---- phase A: 4 tiles' point loads + index math ----
        int ofs[4];
#pragma unroll
        for (int u = 0; u < 4; ++u) {
            int p = (tb + u) * 16 + l15;
            int pc = p < nPoints ? p : nPoints - 1;
            const float px = pts[3 * pc + 0];
            const float py = pts[3 * pc + 1];
            const float pz = pts[3 * pc + 2];
            const int ix = (int)rintf(fminf(fmaxf(px * 127.0f, 0.0f), 127.0f));
            const int iy = (int)rintf(fminf(fmaxf(py * 127.0f, 0.0f), 127.0f));
            const int iz = (int)rintf(fminf(fmaxf(pz * 127.0f, 0.0f), 127.0f));
            ofs[u] = ((((ix << 7) | iy) << 7) | iz) << 4;
        }

        // ---- phase B: all 8 gathers issued before ANY compute ----
        float4 g0[4] = {}, g1[4] = {};
#pragma unroll
        for (int u = 0; u < 4; ++u) {
            if (quad < 2) {
                const float4* gp = reinterpret_cast<const float4*>(grid + ofs[u] + quad * 8);
                g0[u] = gp[0];
                g1[u] = gp[1];
            }
        }
        // Hard scheduling fence: nothing crosses. Forces the 8 dwordx4s
        // above to issue (and live in VGPRs) before the MLP below.
        __builtin_amdgcn_sched_barrier(0);

        // ---- phase C: per-tile MLP ----
        float o[4];
#pragma unroll
        for (int u = 0; u < 4; ++u) {
            half8 bfrag = {};
            if (quad < 2) {
                bfrag[0] = (_Float16)g0[u].x; bfrag[1] = (_Float16)g0[u].y;
                bfrag[2] = (_Float16)g0[u].z; bfrag[3] = (_Float16)g0[u].w;
                bfrag[4] = (_Float16)g1[u].x; bfrag[5] = (_Float16)g1[u].y;
                bfrag[6] = (_Float16)g1[u].z; bfrag[7] = (_Float16)g1[u].w;
            } else if (quad == 2) {
                bfrag[0] = (_Float16)1.0f;  // multiplies the folded b1 column
            }

            // layer 1 (bias via folded K-slot; acc starts at 0)
            float4v C1[4];
#pragma unroll
            for (int t = 0; t < 4; ++t) {
                float4v z = {};
                C1[t] = __builtin_amdgcn_mfma_f32_16x16x32_f16(A1[t], bfrag, z, 0, 0, 0);
            }

            // relu + fp16 pack
            uint32_t P[4][2];
#pragma unroll
            for (int t = 0; t < 4; ++t) {
                const float v0 = fmaxf(C1[t][0], 0.0f);
                const float v1 = fmaxf(C1[t][1], 0.0f);
                const float v2 = fmaxf(C1[t][2], 0.0f);
                const float v3 = fmaxf(C1[t][3], 0.0f);
                P[t][0] = pack_f16x2(v0, v1);
                P[t][1] = pack_f16x2(v2, v3);
            }

            // cross-quad shuffle into layer-2 B fragments
            union Frag { uint32_t u[4]; half8 h; } B2[2];
#pragma unroll
            for (int kk = 0; kk < 2; ++kk) {
                const uint32_t x0a = (uint32_t)__shfl((int)P[2 * kk    ][0], src0);
                const uint32_t x0b = (uint32_t)__shfl((int)P[2 * kk + 1][0], src0);
                const uint32_t x1a = (uint32_t)__shfl((int)P[2 * kk    ][1], src0);
                const uint32_t x1b = (uint32_t)__shfl((int)P[2 * kk + 1][1], src0);
                const uint32_t y0a = (uint32_t)__shfl((int)P[2 * kk    ][0], src1);
                const uint32_t y0b = (uint32_t)__shfl((int)P[2 * kk + 1][0], src1);
                const uint32_t y1a = (uint32_t)__shfl((int)P[2 * kk    ][1], src1);
                const uint32_t y1b = (uint32_t)__shfl((int)P[2 * kk + 1][1], src1);
                B2[kk].u[0] = sel ? x0b : x0a;
                B2[kk].u[1] = sel ? x1b : x1a;
                B2[kk].u[2] = sel ? y0b : y0a;
                B2[kk].u[3] = sel ? y1b : y1a;
            }

            // layer 2
            float4v C2[4];
#pragma unroll
            for (int t = 0; t < 4; ++t) C2[t] = bias2[t];
#pragma unroll
            for (int kk = 0; kk < 2; ++kk)
#pragma unroll
                for (int t = 0; t < 4; ++t)
                    C2[t] = __builtin_amdgcn_mfma_f32_16x16x32_f16(A2[t][kk], B2[kk].h, C2[t], 0, 0, 0);

            // layer 3: dot(relu(h2), w3), reduce across quads
            float z = 0.0f;
#pragma unroll
            for (int t = 0; t < 4; ++t)
#pragma unroll
                for (int r = 0; r < 4; ++r)
                    z = fmaf(fmaxf(C2[t][r], 0.0f), w3v[t][r], z);
            z += __shfl_xor(z, 16);
            z += __shfl_xor(z, 32);
            // tanh(x) = 1 - 2/(exp(2x)+1); exp saturation gives exact +-1 tails
            const float e = __expf(2.0f * (z + bias3));
            o[u] = fmaf(-2.0f, __builtin_amdgcn_rcpf(e + 1.0f), 1.0f);
        }

        // ---- fused epilogue: one coalesced 256B store ----
        const float osel = (quad == 0) ? o[0] : (quad == 1) ? o[1]
                         : (quad == 2) ? o[2] : o[3];
        const int pstore = tb * 16 + lane;
        if (pstore < nPoints) out[pstore] = osel;
    }
}

extern "C" void kernel_launch(void* const* d_in, const int* in_sizes, int n_in,
                              void* d_out, int out_size, void* d_ws, size_t ws_size,
                              hipStream_t stream)
{
    const float* pts  = (const float*)d_in[0];
    const float* grid = (const float*)d_in[1];
    const float* W1   = (const float*)d_in[2];
    const float* b1   = (const float*)d_in[3];
    const float* W2   = (const float*)d_in[4];
    const float* b2   = (const float*)d_in[5];
    const float* W3   = (const float*)d_in[6];
    const float* b3   = (const float*)d_in[7];
    float* out = (float*)d_out;
    const int nPoints = in_sizes[0] / 3;

    // 2048 blocks x 4 waves = 8192 waves; 131072 tiles = 4 batches of 4/wave
    occ_mlp_kernel<<<dim3(2048), dim3(256), 0, stream>>>(
        pts, grid, W1, b1, W2, b2, W3, b3, out, nPoints);
}